// Round 3
// baseline (391.093 us; speedup 1.0000x reference)
//
#include <hip/hip_runtime.h>

// ---------------------------------------------------------------------------
// LiteMLA: B=4, N=4096, C=1024, D=32, h=32 heads.
//   qkv = x @ W_qkv^T            (16384 x 3072, K=1024)   [relu on q,k cols]
//   per (b,h): vk[d,e] = sum_n Vpad[d,n]*reluK[e,n]   (33x32, reduce N=4096)
//              y[d,n]  = (sum_e vk[d,e]*reluQ[e,n]) / (sum_e vk[32,e]*reluQ[e,n] + eps)
//   out = y @ W_proj^T + b_proj  (16384 x 1024, K=1024)
// GEMMs: NT bf16 MFMA 16x16x32, global_load_lds width-16 staging, operand-
// swapped epilogue (N on quad*4+r axis -> vectorized us4/f32x4 stores).
// ---------------------------------------------------------------------------

using us8   = __attribute__((ext_vector_type(8))) unsigned short;
using us4   = __attribute__((ext_vector_type(4))) unsigned short;
using s8v   = __attribute__((ext_vector_type(8))) short;
using f32x4 = __attribute__((ext_vector_type(4))) float;

__device__ __forceinline__ unsigned short f2bf(float f) {
    union { float f; unsigned int u; } c; c.f = f;
    unsigned int r = c.u + 0x7fffu + ((c.u >> 16) & 1u);   // RTN-even
    return (unsigned short)(r >> 16);
}
__device__ __forceinline__ float bf2f(unsigned short u) {
    union { unsigned int u; float f; } c; c.u = ((unsigned int)u) << 16;
    return c.f;
}

// async global->LDS, 16B per lane; LDS dest = wave-uniform base + lane*16
__device__ __forceinline__ void async16(const unsigned short* g, unsigned short* l) {
    __builtin_amdgcn_global_load_lds(
        (const __attribute__((address_space(1))) unsigned int*)g,
        (__attribute__((address_space(3))) unsigned int*)l, 16, 0, 0);
}

// ------------------ fused fp32->bf16 converts + vkws zero ------------------
// segments (in 8-element groups): x | W_qkv | W_proj | vkws-zero
__global__ __launch_bounds__(256)
void prep(const float* __restrict__ x, const float* __restrict__ wq,
          const float* __restrict__ wp, unsigned short* __restrict__ xb,
          unsigned short* __restrict__ wqb, unsigned short* __restrict__ wpb,
          float* __restrict__ vkws) {
    const int NX = 16777216 / 8, NQ = 3145728 / 8, NP = 1048576 / 8, NZ = 135168 / 8;
    int gid = blockIdx.x * 256 + threadIdx.x;
    const float* in; unsigned short* out; int i;
    if (gid < NX)                    { in = x;  out = xb;  i = gid * 8; }
    else if (gid < NX + NQ)          { in = wq; out = wqb; i = (gid - NX) * 8; }
    else if (gid < NX + NQ + NP)     { in = wp; out = wpb; i = (gid - NX - NQ) * 8; }
    else if (gid < NX + NQ + NP + NZ) {
        int z = (gid - NX - NQ - NP) * 8;
        f32x4 zero = {};
        *(f32x4*)(vkws + z) = zero; *(f32x4*)(vkws + z + 4) = zero;
        return;
    } else return;
    float4 a = *(const float4*)(in + i);
    float4 b = *(const float4*)(in + i + 4);
    us8 o;
    o[0] = f2bf(a.x); o[1] = f2bf(a.y); o[2] = f2bf(a.z); o[3] = f2bf(a.w);
    o[4] = f2bf(b.x); o[5] = f2bf(b.y); o[6] = f2bf(b.z); o[7] = f2bf(b.w);
    *(us8*)(out + i) = o;
}

// ----------------------------- bf16 NT GEMM --------------------------------
// C[m,n] = sum_k A[m,k]*Bt[n,k].  128x128 tile, BK=32, 256 threads (4 waves).
// grid: (N/128, M/128)  [x = N-tile so consecutive blocks share an A-tile]
// mfma(bf, af): lane&15 -> m, quad*4+r -> n  => 4 consecutive n per lane.
// MODE 0: store bf16 us4, relu on cols < 2048.  MODE 1: fp32 f32x4 + bias.
template <int MODE>
__global__ __launch_bounds__(256)
void gemm_bt(const unsigned short* __restrict__ A,
             const unsigned short* __restrict__ Bt,
             void* __restrict__ C, const float* __restrict__ bias,
             int M, int N, int K) {
    __shared__ unsigned short As[128 * 32];
    __shared__ unsigned short Bs[128 * 32];

    const int tid  = threadIdx.x;
    const int lane = tid & 63;
    const int wv   = tid >> 6;          // 0..3
    const int wr   = wv >> 1, wc = wv & 1;
    const int tM   = blockIdx.y * 128;
    const int tN   = blockIdx.x * 128;

    f32x4 acc[4][4] = {};

    const unsigned short* Ag = A + (size_t)(tM + wv * 32 + (lane >> 2)) * K + (lane & 3) * 8;
    const unsigned short* Bg = Bt + (size_t)(tN + wv * 32 + (lane >> 2)) * K + (lane & 3) * 8;
    unsigned short* AsW = &As[(wv * 32) * 32];
    unsigned short* BsW = &Bs[(wv * 32) * 32];

    const int mrow = lane & 15;
    const int kq   = (lane >> 4) * 8;

    for (int k0 = 0; k0 < K; k0 += 32) {
        __syncthreads();                       // previous iter's reads done
        async16(Ag + k0,          AsW);
        async16(Ag + 16 * K + k0, AsW + 16 * 32);
        async16(Bg + k0,          BsW);
        async16(Bg + 16 * K + k0, BsW + 16 * 32);
        asm volatile("s_waitcnt vmcnt(0)" ::: "memory");
        __syncthreads();                       // all waves' data in LDS
        s8v af[4], bf[4];
#pragma unroll
        for (int mi = 0; mi < 4; ++mi)
            af[mi] = *(const s8v*)&As[(wr * 64 + mi * 16 + mrow) * 32 + kq];
#pragma unroll
        for (int ni = 0; ni < 4; ++ni)
            bf[ni] = *(const s8v*)&Bs[(wc * 64 + ni * 16 + mrow) * 32 + kq];
#pragma unroll
        for (int mi = 0; mi < 4; ++mi)
#pragma unroll
            for (int ni = 0; ni < 4; ++ni)
                acc[mi][ni] = __builtin_amdgcn_mfma_f32_16x16x32_bf16(
                    bf[ni], af[mi], acc[mi][ni], 0, 0, 0);
    }

    const int quad = lane >> 4;
#pragma unroll
    for (int mi = 0; mi < 4; ++mi) {
        int m = tM + wr * 64 + mi * 16 + (lane & 15);
#pragma unroll
        for (int ni = 0; ni < 4; ++ni) {
            int nbase = tN + wc * 64 + ni * 16 + quad * 4;
            f32x4 v = acc[mi][ni];
            if (MODE == 0) {
                if (nbase < 2048) {
                    v[0] = fmaxf(v[0], 0.f); v[1] = fmaxf(v[1], 0.f);
                    v[2] = fmaxf(v[2], 0.f); v[3] = fmaxf(v[3], 0.f);
                }
                us4 o;
                o[0] = f2bf(v[0]); o[1] = f2bf(v[1]);
                o[2] = f2bf(v[2]); o[3] = f2bf(v[3]);
                *(us4*)&((unsigned short*)C)[(size_t)m * N + nbase] = o;
            } else {
                f32x4 b4 = *(const f32x4*)&bias[nbase];
                v[0] += b4[0]; v[1] += b4[1]; v[2] += b4[2]; v[3] += b4[3];
                *(f32x4*)&((float*)C)[(size_t)m * N + nbase] = v;
            }
        }
    }
}

// ------------- vk partial: 1024 blocks, atomicAdd into vkws ----------------
// grid (128 bh, 8 chunks of 512 tokens). Thread t: e = t&31, d = (t>>5)*4..+3.
__global__ __launch_bounds__(256)
void lite_vk(const unsigned short* __restrict__ qkv, float* __restrict__ vkws) {
    const int bh = blockIdx.x, ch = blockIdx.y;
    const int b = bh >> 5, h = bh & 31;
    __shared__ unsigned short Kt[64 * 32];
    __shared__ unsigned short Vt[64 * 32];
    const int t = threadIdx.x;
    const int e = t & 31, dg = (t >> 5) * 4;
    float acc0 = 0, acc1 = 0, acc2 = 0, acc3 = 0, accK = 0;
    const int lrow = t >> 2, lseg = (t & 3) * 8;
    const int ko = 1024 + h * 32 + lseg;
    const int vo = 2048 + h * 32 + lseg;
    const int rowbase = b * 4096 + ch * 512;

    for (int n0 = 0; n0 < 512; n0 += 64) {
        int g = (rowbase + n0 + lrow) * 3072;
        us8 kv = *(const us8*)(qkv + g + ko);
        us8 vv = *(const us8*)(qkv + g + vo);
        __syncthreads();
        *(us8*)&Kt[lrow * 32 + lseg] = kv;
        *(us8*)&Vt[lrow * 32 + lseg] = vv;
        __syncthreads();
#pragma unroll 8
        for (int nn = 0; nn < 64; ++nn) {
            float kk = bf2f(Kt[nn * 32 + e]);       // K already relu'd in GEMM1
            us4 v4 = *(const us4*)&Vt[nn * 32 + dg];
            acc0 += bf2f(v4[0]) * kk;
            acc1 += bf2f(v4[1]) * kk;
            acc2 += bf2f(v4[2]) * kk;
            acc3 += bf2f(v4[3]) * kk;
            accK += kk;
        }
    }
    float* vkb = vkws + bh * (33 * 32);
    atomicAdd(&vkb[(dg + 0) * 32 + e], acc0);
    atomicAdd(&vkb[(dg + 1) * 32 + e], acc1);
    atomicAdd(&vkb[(dg + 2) * 32 + e], acc2);
    atomicAdd(&vkb[(dg + 3) * 32 + e], acc3);
    if (dg == 0) atomicAdd(&vkb[32 * 32 + e], accK);
}

// --------------- y = (vk @ reluQ) / pad-row, MFMA K=32 ---------------------
// grid (128 bh, 16 chunks of 256 tokens), 256 threads (4 waves x 64 tokens).
// mfma(vk_frag, q_frag): lane&15 -> token, quad*4+r -> d  => us4 stores.
__global__ __launch_bounds__(256)
void lite_apply(const unsigned short* __restrict__ qkv,
                const float* __restrict__ vkws,
                unsigned short* __restrict__ yb) {
    const int bh = blockIdx.x, nb = blockIdx.y;
    const int b = bh >> 5, h = bh & 31;
    __shared__ unsigned short vkh[48 * 32];
    __shared__ unsigned short vkl[48 * 32];
    const int t = threadIdx.x;
    for (int i = t; i < 48 * 32; i += 256) {
        float v = (i < 33 * 32) ? vkws[bh * (33 * 32) + i] : 0.f;
        unsigned short hi = f2bf(v);
        vkh[i] = hi;
        vkl[i] = f2bf(v - bf2f(hi));
    }
    __syncthreads();

    const int lane = t & 63, wv = t >> 6;
    const int col = lane & 15, quad = lane >> 4;
    s8v b0h = *(const s8v*)&vkh[(col)      * 32 + quad * 8];
    s8v b0l = *(const s8v*)&vkl[(col)      * 32 + quad * 8];
    s8v b1h = *(const s8v*)&vkh[(16 + col) * 32 + quad * 8];
    s8v b1l = *(const s8v*)&vkl[(16 + col) * 32 + quad * 8];
    s8v b2h = *(const s8v*)&vkh[(32 + col) * 32 + quad * 8];
    s8v b2l = *(const s8v*)&vkl[(32 + col) * 32 + quad * 8];

    const int ntile = nb * 256 + wv * 64;
#pragma unroll
    for (int mi = 0; mi < 4; ++mi) {
        int tok = ntile + mi * 16 + col;       // token = lane&15 (B-operand row)
        const unsigned short* qp =
            qkv + (size_t)(b * 4096 + tok) * 3072 + h * 32 + quad * 8;
        s8v a = *(const s8v*)qp;
        f32x4 n0 = {}, n1 = {}, dd = {};
        n0 = __builtin_amdgcn_mfma_f32_16x16x32_bf16(b0h, a, n0, 0, 0, 0);
        n0 = __builtin_amdgcn_mfma_f32_16x16x32_bf16(b0l, a, n0, 0, 0, 0);
        n1 = __builtin_amdgcn_mfma_f32_16x16x32_bf16(b1h, a, n1, 0, 0, 0);
        n1 = __builtin_amdgcn_mfma_f32_16x16x32_bf16(b1l, a, n1, 0, 0, 0);
        dd = __builtin_amdgcn_mfma_f32_16x16x32_bf16(b2h, a, dd, 0, 0, 0);
        dd = __builtin_amdgcn_mfma_f32_16x16x32_bf16(b2l, a, dd, 0, 0, 0);
        // dd[0] on quad==0 lanes = pad-row dot for token col; broadcast
        float den  = __shfl(dd[0], col, 64);
        float rinv = 1.f / (den + 1e-15f);
        us4 o0, o1;
#pragma unroll
        for (int r = 0; r < 4; ++r) {
            o0[r] = f2bf(n0[r] * rinv);
            o1[r] = f2bf(n1[r] * rinv);
        }
        size_t o = (size_t)(b * 4096 + tok) * 1024 + h * 32;
        *(us4*)&yb[o + quad * 4]      = o0;
        *(us4*)&yb[o + 16 + quad * 4] = o1;
    }
}

// ---------------------------------------------------------------------------
extern "C" void kernel_launch(void* const* d_in, const int* in_sizes, int n_in,
                              void* d_out, int out_size, void* d_ws, size_t ws_size,
                              hipStream_t stream) {
    const float* x     = (const float*)d_in[0];   // (4,4096,1024)
    const float* Wqkv  = (const float*)d_in[1];   // (3072,1024)
    const float* Wproj = (const float*)d_in[2];   // (1024,1024)
    const float* bproj = (const float*)d_in[3];   // (1024,)
    float* out = (float*)d_out;                   // (4,4096,1024) fp32

    const int M = 16384, Cdim = 1024, O1 = 3072;

    unsigned short* xb     = (unsigned short*)d_ws;
    unsigned short* wqkvb  = xb + (size_t)M * Cdim;
    unsigned short* wprojb = wqkvb + (size_t)O1 * Cdim;
    unsigned short* qkvb   = wprojb + (size_t)Cdim * Cdim;
    unsigned short* ybuf   = qkvb + (size_t)M * O1;
    float* vkws            = (float*)(ybuf + (size_t)M * Cdim);
    // ws use: ~177 MB

    const int PREP_GROUPS = (16777216 + 3145728 + 1048576 + 135168) / 8;
    prep<<<(PREP_GROUPS + 255) / 256, 256, 0, stream>>>(
        x, Wqkv, Wproj, xb, wqkvb, wprojb, vkws);

    gemm_bt<0><<<dim3(O1 / 128, M / 128), 256, 0, stream>>>(
        xb, wqkvb, (void*)qkvb, nullptr, M, O1, Cdim);

    lite_vk<<<dim3(128, 8), 256, 0, stream>>>(qkvb, vkws);
    lite_apply<<<dim3(128, 16), 256, 0, stream>>>(qkvb, vkws, ybuf);

    gemm_bt<1><<<dim3(Cdim / 128, M / 128), 256, 0, stream>>>(
        ybuf, wprojb, (void*)out, bproj, M, Cdim, Cdim);
}

// Round 4
// 378.198 us; speedup vs baseline: 1.0341x; 1.0341x over previous
//
#include <hip/hip_runtime.h>

// ---------------------------------------------------------------------------
// LiteMLA: B=4, N=4096, C=1024, D=32, h=32 heads.
//   qkv = x @ W_qkv^T            (16384 x 3072, K=1024)   [relu on q,k cols]
//   per (b,h): vk[d,e] = sum_n Vpad[d,n]*reluK[e,n]   (33x32, reduce N=4096)
//              y[d,n]  = (sum_e vk[d,e]*reluQ[e,n]) / (sum_e vk[32,e]*reluQ[e,n] + eps)
//   out = y @ W_proj^T + b_proj  (16384 x 1024, K=1024)
// GEMMs: NT bf16 MFMA 16x16x32, global_load_lds width-16 staging, BK=64 via
// two BK=32 panels (one barrier pair per 64 K), M-major swizzled grid.
// ---------------------------------------------------------------------------

using us8   = __attribute__((ext_vector_type(8))) unsigned short;
using us4   = __attribute__((ext_vector_type(4))) unsigned short;
using s8v   = __attribute__((ext_vector_type(8))) short;
using f32x4 = __attribute__((ext_vector_type(4))) float;

__device__ __forceinline__ unsigned short f2bf(float f) {
    union { float f; unsigned int u; } c; c.f = f;
    unsigned int r = c.u + 0x7fffu + ((c.u >> 16) & 1u);   // RTN-even
    return (unsigned short)(r >> 16);
}
__device__ __forceinline__ float bf2f(unsigned short u) {
    union { unsigned int u; float f; } c; c.u = ((unsigned int)u) << 16;
    return c.f;
}

// async global->LDS, 16B per lane; LDS dest = wave-uniform base + lane*16
__device__ __forceinline__ void async16(const unsigned short* g, unsigned short* l) {
    __builtin_amdgcn_global_load_lds(
        (const __attribute__((address_space(1))) unsigned int*)g,
        (__attribute__((address_space(3))) unsigned int*)l, 16, 0, 0);
}

// ------------------ fused fp32->bf16 converts + vkws zero ------------------
__global__ __launch_bounds__(256)
void prep(const float* __restrict__ x, const float* __restrict__ wq,
          const float* __restrict__ wp, unsigned short* __restrict__ xb,
          unsigned short* __restrict__ wqb, unsigned short* __restrict__ wpb,
          float* __restrict__ vkws) {
    const int NX = 16777216 / 8, NQ = 3145728 / 8, NP = 1048576 / 8, NZ = 135168 / 8;
    int gid = blockIdx.x * 256 + threadIdx.x;
    const float* in; unsigned short* out; int i;
    if (gid < NX)                    { in = x;  out = xb;  i = gid * 8; }
    else if (gid < NX + NQ)          { in = wq; out = wqb; i = (gid - NX) * 8; }
    else if (gid < NX + NQ + NP)     { in = wp; out = wpb; i = (gid - NX - NQ) * 8; }
    else if (gid < NX + NQ + NP + NZ) {
        int z = (gid - NX - NQ - NP) * 8;
        f32x4 zero = {};
        *(f32x4*)(vkws + z) = zero; *(f32x4*)(vkws + z + 4) = zero;
        return;
    } else return;
    float4 a = *(const float4*)(in + i);
    float4 b = *(const float4*)(in + i + 4);
    us8 o;
    o[0] = f2bf(a.x); o[1] = f2bf(a.y); o[2] = f2bf(a.z); o[3] = f2bf(a.w);
    o[4] = f2bf(b.x); o[5] = f2bf(b.y); o[6] = f2bf(b.z); o[7] = f2bf(b.w);
    *(us8*)(out + i) = o;
}

// ----------------------------- bf16 NT GEMM --------------------------------
// C[m,n] = sum_k A[m,k]*Bt[n,k].  128x128 tile, BK=64 (two 32-panels), 256
// threads (4 waves), each wave 64x64 via 4x4 grid of 16x16x32 MFMAs x2 halves.
// 1D grid, swizzle: 128-block groups cover 16 M-tiles x 8 N-tiles (L2 fit).
// MODE 0: store bf16, relu on cols < 2048 (q,k).  MODE 1: fp32 + bias.
template <int MODE>
__global__ __launch_bounds__(256)
void gemm_bt(const unsigned short* __restrict__ A,
             const unsigned short* __restrict__ Bt,
             void* __restrict__ C, const float* __restrict__ bias,
             int M, int N, int K) {
    __shared__ unsigned short As0[128 * 32], As1[128 * 32];
    __shared__ unsigned short Bs0[128 * 32], Bs1[128 * 32];

    const int tid  = threadIdx.x;
    const int lane = tid & 63;
    const int wv   = tid >> 6;          // 0..3
    const int wr   = wv >> 1, wc = wv & 1;

    // swizzle: groups of 8 N-tiles; within a group sweep M (M/128=128 tiles)
    const int MT  = M >> 7;
    const int bpg = MT * 8;
    const int g   = blockIdx.x / bpg;
    const int r   = blockIdx.x % bpg;
    const int tM  = (r >> 3) * 128;
    const int tN  = (g * 8 + (r & 7)) * 128;

    f32x4 acc[4][4] = {};

    const unsigned short* Ag = A + (size_t)(tM + wv * 32 + (lane >> 2)) * K + (lane & 3) * 8;
    const unsigned short* Bg = Bt + (size_t)(tN + wv * 32 + (lane >> 2)) * K + (lane & 3) * 8;
    const int wo = wv * 32 * 32;

    const int mrow = lane & 15;
    const int kq   = (lane >> 4) * 8;

    for (int k0 = 0; k0 < K; k0 += 64) {
        __syncthreads();                       // previous iter's reads done
        async16(Ag + k0,               &As0[wo]);
        async16(Ag + k0 + 16 * K,      &As0[wo + 16 * 32]);
        async16(Ag + k0 + 32,          &As1[wo]);
        async16(Ag + k0 + 32 + 16 * K, &As1[wo + 16 * 32]);
        async16(Bg + k0,               &Bs0[wo]);
        async16(Bg + k0 + 16 * K,      &Bs0[wo + 16 * 32]);
        async16(Bg + k0 + 32,          &Bs1[wo]);
        async16(Bg + k0 + 32 + 16 * K, &Bs1[wo + 16 * 32]);
        asm volatile("s_waitcnt vmcnt(0)" ::: "memory");
        __syncthreads();                       // all waves' data in LDS
        s8v af[4], bf[4];
#pragma unroll
        for (int mi = 0; mi < 4; ++mi)
            af[mi] = *(const s8v*)&As0[(wr * 64 + mi * 16 + mrow) * 32 + kq];
#pragma unroll
        for (int ni = 0; ni < 4; ++ni)
            bf[ni] = *(const s8v*)&Bs0[(wc * 64 + ni * 16 + mrow) * 32 + kq];
#pragma unroll
        for (int mi = 0; mi < 4; ++mi)
#pragma unroll
            for (int ni = 0; ni < 4; ++ni)
                acc[mi][ni] = __builtin_amdgcn_mfma_f32_16x16x32_bf16(
                    af[mi], bf[ni], acc[mi][ni], 0, 0, 0);
#pragma unroll
        for (int mi = 0; mi < 4; ++mi)
            af[mi] = *(const s8v*)&As1[(wr * 64 + mi * 16 + mrow) * 32 + kq];
#pragma unroll
        for (int ni = 0; ni < 4; ++ni)
            bf[ni] = *(const s8v*)&Bs1[(wc * 64 + ni * 16 + mrow) * 32 + kq];
#pragma unroll
        for (int mi = 0; mi < 4; ++mi)
#pragma unroll
            for (int ni = 0; ni < 4; ++ni)
                acc[mi][ni] = __builtin_amdgcn_mfma_f32_16x16x32_bf16(
                    af[mi], bf[ni], acc[mi][ni], 0, 0, 0);
    }

    const int crow0 = (lane >> 4) * 4;
    const int ccol  = lane & 15;
#pragma unroll
    for (int mi = 0; mi < 4; ++mi)
#pragma unroll
        for (int ni = 0; ni < 4; ++ni) {
            int row = tM + wr * 64 + mi * 16 + crow0;
            int col = tN + wc * 64 + ni * 16 + ccol;
#pragma unroll
            for (int r2 = 0; r2 < 4; ++r2) {
                float v = acc[mi][ni][r2];
                if (MODE == 0) {
                    if (col < 2048) v = fmaxf(v, 0.f);
                    ((unsigned short*)C)[(size_t)(row + r2) * N + col] = f2bf(v);
                } else {
                    ((float*)C)[(size_t)(row + r2) * N + col] = v + bias[col];
                }
            }
        }
}

// ------------- vk partial: 1024 blocks, atomicAdd into vkws ----------------
__global__ __launch_bounds__(256)
void lite_vk(const unsigned short* __restrict__ qkv, float* __restrict__ vkws) {
    const int bh = blockIdx.x, ch = blockIdx.y;
    const int b = bh >> 5, h = bh & 31;
    __shared__ unsigned short Kt[64 * 32];
    __shared__ unsigned short Vt[64 * 32];
    const int t = threadIdx.x;
    const int e = t & 31, dg = (t >> 5) * 4;
    float acc0 = 0, acc1 = 0, acc2 = 0, acc3 = 0, accK = 0;
    const int lrow = t >> 2, lseg = (t & 3) * 8;
    const int ko = 1024 + h * 32 + lseg;
    const int vo = 2048 + h * 32 + lseg;
    const int rowbase = b * 4096 + ch * 512;

    for (int n0 = 0; n0 < 512; n0 += 64) {
        int g = (rowbase + n0 + lrow) * 3072;
        us8 kv = *(const us8*)(qkv + g + ko);
        us8 vv = *(const us8*)(qkv + g + vo);
        __syncthreads();
        *(us8*)&Kt[lrow * 32 + lseg] = kv;
        *(us8*)&Vt[lrow * 32 + lseg] = vv;
        __syncthreads();
#pragma unroll 8
        for (int nn = 0; nn < 64; ++nn) {
            float kk = bf2f(Kt[nn * 32 + e]);       // K already relu'd in GEMM1
            us4 v4 = *(const us4*)&Vt[nn * 32 + dg];
            acc0 += bf2f(v4[0]) * kk;
            acc1 += bf2f(v4[1]) * kk;
            acc2 += bf2f(v4[2]) * kk;
            acc3 += bf2f(v4[3]) * kk;
            accK += kk;
        }
    }
    float* vkb = vkws + bh * (33 * 32);
    atomicAdd(&vkb[(dg + 0) * 32 + e], acc0);
    atomicAdd(&vkb[(dg + 1) * 32 + e], acc1);
    atomicAdd(&vkb[(dg + 2) * 32 + e], acc2);
    atomicAdd(&vkb[(dg + 3) * 32 + e], acc3);
    if (dg == 0) atomicAdd(&vkb[32 * 32 + e], accK);
}

// --------------- y = (vk @ reluQ) / pad-row, MFMA K=32 ---------------------
__global__ __launch_bounds__(256)
void lite_apply(const unsigned short* __restrict__ qkv,
                const float* __restrict__ vkws,
                unsigned short* __restrict__ yb) {
    const int bh = blockIdx.x, nb = blockIdx.y;
    const int b = bh >> 5, h = bh & 31;
    __shared__ unsigned short vkh[48 * 32];
    __shared__ unsigned short vkl[48 * 32];
    const int t = threadIdx.x;
    for (int i = t; i < 48 * 32; i += 256) {
        float v = (i < 33 * 32) ? vkws[bh * (33 * 32) + i] : 0.f;
        unsigned short hi = f2bf(v);
        vkh[i] = hi;
        vkl[i] = f2bf(v - bf2f(hi));
    }
    __syncthreads();

    const int lane = t & 63, wv = t >> 6;
    const int col = lane & 15, quad = lane >> 4;
    s8v b0h = *(const s8v*)&vkh[(col)      * 32 + quad * 8];
    s8v b0l = *(const s8v*)&vkl[(col)      * 32 + quad * 8];
    s8v b1h = *(const s8v*)&vkh[(16 + col) * 32 + quad * 8];
    s8v b1l = *(const s8v*)&vkl[(16 + col) * 32 + quad * 8];
    s8v b2h = *(const s8v*)&vkh[(32 + col) * 32 + quad * 8];
    s8v b2l = *(const s8v*)&vkl[(32 + col) * 32 + quad * 8];

    const int ntile = nb * 256 + wv * 64;
#pragma unroll
    for (int mi = 0; mi < 4; ++mi) {
        int tok = ntile + mi * 16 + col;       // token = lane&15 (B-operand row)
        const unsigned short* qp =
            qkv + (size_t)(b * 4096 + tok) * 3072 + h * 32 + quad * 8;
        s8v a = *(const s8v*)qp;
        f32x4 n0 = {}, n1 = {}, dd = {};
        n0 = __builtin_amdgcn_mfma_f32_16x16x32_bf16(b0h, a, n0, 0, 0, 0);
        n0 = __builtin_amdgcn_mfma_f32_16x16x32_bf16(b0l, a, n0, 0, 0, 0);
        n1 = __builtin_amdgcn_mfma_f32_16x16x32_bf16(b1h, a, n1, 0, 0, 0);
        n1 = __builtin_amdgcn_mfma_f32_16x16x32_bf16(b1l, a, n1, 0, 0, 0);
        dd = __builtin_amdgcn_mfma_f32_16x16x32_bf16(b2h, a, dd, 0, 0, 0);
        dd = __builtin_amdgcn_mfma_f32_16x16x32_bf16(b2l, a, dd, 0, 0, 0);
        float den  = __shfl(dd[0], col, 64);
        float rinv = 1.f / (den + 1e-15f);
        us4 o0, o1;
#pragma unroll
        for (int r = 0; r < 4; ++r) {
            o0[r] = f2bf(n0[r] * rinv);
            o1[r] = f2bf(n1[r] * rinv);
        }
        size_t o = (size_t)(b * 4096 + tok) * 1024 + h * 32;
        *(us4*)&yb[o + quad * 4]      = o0;
        *(us4*)&yb[o + 16 + quad * 4] = o1;
    }
}

// ---------------------------------------------------------------------------
extern "C" void kernel_launch(void* const* d_in, const int* in_sizes, int n_in,
                              void* d_out, int out_size, void* d_ws, size_t ws_size,
                              hipStream_t stream) {
    const float* x     = (const float*)d_in[0];   // (4,4096,1024)
    const float* Wqkv  = (const float*)d_in[1];   // (3072,1024)
    const float* Wproj = (const float*)d_in[2];   // (1024,1024)
    const float* bproj = (const float*)d_in[3];   // (1024,)
    float* out = (float*)d_out;                   // (4,4096,1024) fp32

    const int M = 16384, Cdim = 1024, O1 = 3072;

    unsigned short* xb     = (unsigned short*)d_ws;
    unsigned short* wqkvb  = xb + (size_t)M * Cdim;
    unsigned short* wprojb = wqkvb + (size_t)O1 * Cdim;
    unsigned short* qkvb   = wprojb + (size_t)Cdim * Cdim;
    unsigned short* ybuf   = qkvb + (size_t)M * O1;
    float* vkws            = (float*)(ybuf + (size_t)M * Cdim);
    // ws use: ~177 MB

    const int PREP_GROUPS = (16777216 + 3145728 + 1048576 + 135168) / 8;
    prep<<<(PREP_GROUPS + 255) / 256, 256, 0, stream>>>(
        x, Wqkv, Wproj, xb, wqkvb, wprojb, vkws);

    gemm_bt<0><<<(M / 128) * (O1 / 128), 256, 0, stream>>>(
        xb, wqkvb, (void*)qkvb, nullptr, M, O1, Cdim);

    lite_vk<<<dim3(128, 8), 256, 0, stream>>>(qkvb, vkws);
    lite_apply<<<dim3(128, 16), 256, 0, stream>>>(qkvb, vkws, ybuf);

    gemm_bt<1><<<(M / 128) * (Cdim / 128), 256, 0, stream>>>(
        ybuf, wprojb, (void*)out, bproj, M, Cdim, Cdim);
}

// Round 6
// 354.754 us; speedup vs baseline: 1.1024x; 1.0661x over previous
//
#include <hip/hip_runtime.h>

// ---------------------------------------------------------------------------
// LiteMLA: B=4, N=4096, C=1024, D=32, h=32 heads.
//   qkv = x @ W_qkv^T            (16384 x 3072, K=1024)   [relu on q,k cols]
//   per (b,h): vk[d,e] = sum_n Vpad[d,n]*reluK[e,n]   (33x32, reduce N=4096)
//              y[d,n]  = (sum_e vk[d,e]*reluQ[e,n]) / (sum_e vk[32,e]*reluQ[e,n] + eps)
//   out = y @ W_proj^T + b_proj  (16384 x 1024, K=1024)
// gemm1 stores Q token-major (stride 1024) and K/V TRANSPOSED (kvT[b][ch][n])
// so lite_vk is a clean NT MFMA GEMM over token-contiguous rows.
// ---------------------------------------------------------------------------

using us8   = __attribute__((ext_vector_type(8))) unsigned short;
using us4   = __attribute__((ext_vector_type(4))) unsigned short;
using s8v   = __attribute__((ext_vector_type(8))) short;
using f32x4 = __attribute__((ext_vector_type(4))) float;

__device__ __forceinline__ unsigned short f2bf(float f) {
    union { float f; unsigned int u; } c; c.f = f;
    unsigned int r = c.u + 0x7fffu + ((c.u >> 16) & 1u);   // RTN-even
    return (unsigned short)(r >> 16);
}
__device__ __forceinline__ float bf2f(unsigned short u) {
    union { unsigned int u; float f; } c; c.u = ((unsigned int)u) << 16;
    return c.f;
}

// async global->LDS, 16B per lane; LDS dest = wave-uniform base + lane*16
__device__ __forceinline__ void async16(const unsigned short* g, unsigned short* l) {
    __builtin_amdgcn_global_load_lds(
        (const __attribute__((address_space(1))) unsigned int*)g,
        (__attribute__((address_space(3))) unsigned int*)l, 16, 0, 0);
}

// ------------------ fused fp32->bf16 converts + vkws zero ------------------
__global__ __launch_bounds__(256)
void prep(const float* __restrict__ x, const float* __restrict__ wq,
          const float* __restrict__ wp, unsigned short* __restrict__ xb,
          unsigned short* __restrict__ wqb, unsigned short* __restrict__ wpb,
          float* __restrict__ vkws) {
    const int NX = 16777216 / 8, NQ = 3145728 / 8, NP = 1048576 / 8, NZ = 135168 / 8;
    int gid = blockIdx.x * 256 + threadIdx.x;
    const float* in; unsigned short* out; int i;
    if (gid < NX)                    { in = x;  out = xb;  i = gid * 8; }
    else if (gid < NX + NQ)          { in = wq; out = wqb; i = (gid - NX) * 8; }
    else if (gid < NX + NQ + NP)     { in = wp; out = wpb; i = (gid - NX - NQ) * 8; }
    else if (gid < NX + NQ + NP + NZ) {
        int z = (gid - NX - NQ - NP) * 8;
        f32x4 zero = {};
        *(f32x4*)(vkws + z) = zero; *(f32x4*)(vkws + z + 4) = zero;
        return;
    } else return;
    float4 a = *(const float4*)(in + i);
    float4 b = *(const float4*)(in + i + 4);
    us8 o;
    o[0] = f2bf(a.x); o[1] = f2bf(a.y); o[2] = f2bf(a.z); o[3] = f2bf(a.w);
    o[4] = f2bf(b.x); o[5] = f2bf(b.y); o[6] = f2bf(b.z); o[7] = f2bf(b.w);
    *(us8*)(out + i) = o;
}

// ----------------------------- bf16 NT GEMM --------------------------------
// C[m,n] = sum_k A[m,k]*Bt[n,k].  128x128 tile, BK=64 (two 32-panels), 256
// threads (4 waves), each wave 64x64 via 4x4 grid of 16x16x32 MFMAs x2 halves.
// 1D grid, swizzle: groups cover 8 N-tiles x all M-tiles.
// MODE 0: cols<1024 -> Cq token-major bf16 (stride 1024, relu);
//         cols>=1024 -> kvT[b][ch][n] transposed bf16 (relu iff col<2048).
// MODE 1: fp32 + bias to C (stride N).
template <int MODE>
__global__ __launch_bounds__(256)
void gemm_bt(const unsigned short* __restrict__ A,
             const unsigned short* __restrict__ Bt,
             void* __restrict__ C, unsigned short* __restrict__ kvT,
             const float* __restrict__ bias,
             int M, int N, int K) {
    __shared__ unsigned short As0[128 * 32], As1[128 * 32];
    __shared__ unsigned short Bs0[128 * 32], Bs1[128 * 32];

    const int tid  = threadIdx.x;
    const int lane = tid & 63;
    const int wv   = tid >> 6;          // 0..3
    const int wr   = wv >> 1, wc = wv & 1;

    const int MT  = M >> 7;
    const int bpg = MT * 8;
    const int g   = blockIdx.x / bpg;
    const int r   = blockIdx.x % bpg;
    const int tM  = (r >> 3) * 128;
    const int tN  = (g * 8 + (r & 7)) * 128;

    f32x4 acc[4][4] = {};

    const unsigned short* Ag = A + (size_t)(tM + wv * 32 + (lane >> 2)) * K + (lane & 3) * 8;
    const unsigned short* Bg = Bt + (size_t)(tN + wv * 32 + (lane >> 2)) * K + (lane & 3) * 8;
    const int wo = wv * 32 * 32;

    const int mrow = lane & 15;
    const int kq   = (lane >> 4) * 8;

    for (int k0 = 0; k0 < K; k0 += 64) {
        __syncthreads();
        async16(Ag + k0,               &As0[wo]);
        async16(Ag + k0 + 16 * K,      &As0[wo + 16 * 32]);
        async16(Ag + k0 + 32,          &As1[wo]);
        async16(Ag + k0 + 32 + 16 * K, &As1[wo + 16 * 32]);
        async16(Bg + k0,               &Bs0[wo]);
        async16(Bg + k0 + 16 * K,      &Bs0[wo + 16 * 32]);
        async16(Bg + k0 + 32,          &Bs1[wo]);
        async16(Bg + k0 + 32 + 16 * K, &Bs1[wo + 16 * 32]);
        asm volatile("s_waitcnt vmcnt(0)" ::: "memory");
        __syncthreads();
        s8v af[4], bf[4];
#pragma unroll
        for (int mi = 0; mi < 4; ++mi)
            af[mi] = *(const s8v*)&As0[(wr * 64 + mi * 16 + mrow) * 32 + kq];
#pragma unroll
        for (int ni = 0; ni < 4; ++ni)
            bf[ni] = *(const s8v*)&Bs0[(wc * 64 + ni * 16 + mrow) * 32 + kq];
#pragma unroll
        for (int mi = 0; mi < 4; ++mi)
#pragma unroll
            for (int ni = 0; ni < 4; ++ni)
                acc[mi][ni] = __builtin_amdgcn_mfma_f32_16x16x32_bf16(
                    af[mi], bf[ni], acc[mi][ni], 0, 0, 0);
#pragma unroll
        for (int mi = 0; mi < 4; ++mi)
            af[mi] = *(const s8v*)&As1[(wr * 64 + mi * 16 + mrow) * 32 + kq];
#pragma unroll
        for (int ni = 0; ni < 4; ++ni)
            bf[ni] = *(const s8v*)&Bs1[(wc * 64 + ni * 16 + mrow) * 32 + kq];
#pragma unroll
        for (int mi = 0; mi < 4; ++mi)
#pragma unroll
            for (int ni = 0; ni < 4; ++ni)
                acc[mi][ni] = __builtin_amdgcn_mfma_f32_16x16x32_bf16(
                    af[mi], bf[ni], acc[mi][ni], 0, 0, 0);
    }

    const int crow0 = (lane >> 4) * 4;
    const int ccol  = lane & 15;
    if (MODE == 0 && tN >= 1024) {
        // transposed store: kvT[(b*2048 + ch)*4096 + n], n contiguous over r
        const int b2 = tM >> 12;
        const int nb0 = (tM & 4095) + wr * 64;
#pragma unroll
        for (int mi = 0; mi < 4; ++mi) {
            int nbase = nb0 + mi * 16 + crow0;
#pragma unroll
            for (int ni = 0; ni < 4; ++ni) {
                int col = tN + wc * 64 + ni * 16 + ccol;
                f32x4 v = acc[mi][ni];
                if (col < 2048) {
                    v[0] = fmaxf(v[0], 0.f); v[1] = fmaxf(v[1], 0.f);
                    v[2] = fmaxf(v[2], 0.f); v[3] = fmaxf(v[3], 0.f);
                }
                us4 o;
                o[0] = f2bf(v[0]); o[1] = f2bf(v[1]);
                o[2] = f2bf(v[2]); o[3] = f2bf(v[3]);
                *(us4*)&kvT[((size_t)b2 * 2048 + (col - 1024)) * 4096 + nbase] = o;
            }
        }
    } else {
#pragma unroll
        for (int mi = 0; mi < 4; ++mi)
#pragma unroll
            for (int ni = 0; ni < 4; ++ni) {
                int row = tM + wr * 64 + mi * 16 + crow0;
                int col = tN + wc * 64 + ni * 16 + ccol;
#pragma unroll
                for (int r2 = 0; r2 < 4; ++r2) {
                    float v = acc[mi][ni][r2];
                    if (MODE == 0) {
                        v = fmaxf(v, 0.f);   // Q region (col<1024) always relu'd
                        ((unsigned short*)C)[(size_t)(row + r2) * 1024 + col] = f2bf(v);
                    } else {
                        ((float*)C)[(size_t)(row + r2) * N + col] = v + bias[col];
                    }
                }
            }
    }
}

// ---------------- vk = Vpad @ reluK^T via MFMA over kvT --------------------
// grid (128 bh, 8 ck of 512 tokens). M=32 (d), N=32 (e), K=tokens.
// Pad row (all-ones V) = colsum of K via constant-ones A-fragment.
__global__ __launch_bounds__(256)
void lite_vk(const unsigned short* __restrict__ kvT, float* __restrict__ vkws) {
    const int bh = blockIdx.x, ck = blockIdx.y;
    const int b = bh >> 5, h = bh & 31;
    const int S = 136;                       // LDS row stride (u16)
    __shared__ unsigned short Ks[32 * S];
    __shared__ unsigned short Vs[32 * S];
    __shared__ float Rs[4][1088];
    const int t = threadIdx.x, lane = t & 63, wv = t >> 6;
    const unsigned short* Kp = kvT + ((size_t)b * 2048 + h * 32) * 4096 + ck * 512;
    const unsigned short* Vp = kvT + ((size_t)b * 2048 + 1024 + h * 32) * 4096 + ck * 512;
    const int sr = t >> 3, ss = (t & 7) * 16;   // stage: row 0..31, 16-tok seg
    f32x4 acc00 = {}, acc01 = {}, acc10 = {}, acc11 = {}, accO0 = {}, accO1 = {};
    s8v ones;
#pragma unroll
    for (int j = 0; j < 8; ++j) ones[j] = (short)0x3F80;   // 1.0 bf16
    const int mrow = lane & 15, kq = (lane >> 4) * 8;

    for (int tile = 0; tile < 4; ++tile) {
        int go = tile * 128 + ss;
        us8 k0v = *(const us8*)(Kp + (size_t)sr * 4096 + go);
        us8 k1v = *(const us8*)(Kp + (size_t)sr * 4096 + go + 8);
        us8 v0v = *(const us8*)(Vp + (size_t)sr * 4096 + go);
        us8 v1v = *(const us8*)(Vp + (size_t)sr * 4096 + go + 8);
        __syncthreads();
        *(us8*)&Ks[sr * S + ss]     = k0v;
        *(us8*)&Ks[sr * S + ss + 8] = k1v;
        *(us8*)&Vs[sr * S + ss]     = v0v;
        *(us8*)&Vs[sr * S + ss + 8] = v1v;
        __syncthreads();
        int ko = wv * 32 + kq;               // wave wv takes 32-token slice
        s8v a0 = *(const s8v*)&Vs[(mrow)      * S + ko];
        s8v a1 = *(const s8v*)&Vs[(16 + mrow) * S + ko];
        s8v b0 = *(const s8v*)&Ks[(mrow)      * S + ko];
        s8v b1 = *(const s8v*)&Ks[(16 + mrow) * S + ko];
        acc00 = __builtin_amdgcn_mfma_f32_16x16x32_bf16(a0, b0, acc00, 0, 0, 0);
        acc01 = __builtin_amdgcn_mfma_f32_16x16x32_bf16(a0, b1, acc01, 0, 0, 0);
        acc10 = __builtin_amdgcn_mfma_f32_16x16x32_bf16(a1, b0, acc10, 0, 0, 0);
        acc11 = __builtin_amdgcn_mfma_f32_16x16x32_bf16(a1, b1, acc11, 0, 0, 0);
        accO0 = __builtin_amdgcn_mfma_f32_16x16x32_bf16(ones, b0, accO0, 0, 0, 0);
        accO1 = __builtin_amdgcn_mfma_f32_16x16x32_bf16(ones, b1, accO1, 0, 0, 0);
    }

    // per-wave partials -> LDS, then cross-wave reduce + atomicAdd
    const int ccol = lane & 15, crow = (lane >> 4) * 4;
    float* R = Rs[wv];
#pragma unroll
    for (int r2 = 0; r2 < 4; ++r2) {
        R[(crow + r2) * 32 + ccol]           = acc00[r2];
        R[(crow + r2) * 32 + 16 + ccol]      = acc01[r2];
        R[(16 + crow + r2) * 32 + ccol]      = acc10[r2];
        R[(16 + crow + r2) * 32 + 16 + ccol] = acc11[r2];
    }
    if ((lane >> 4) == 0) {                  // C row 0 lives on quad 0, r=0
        R[1024 + ccol]      = accO0[0];
        R[1024 + 16 + ccol] = accO1[0];
    }
    __syncthreads();
    float* vkb = vkws + bh * (33 * 32);
    for (int i = t; i < 1056; i += 256) {
        float s = Rs[0][i] + Rs[1][i] + Rs[2][i] + Rs[3][i];
        atomicAdd(&vkb[i], s);
    }
}

// --------------- y = (vk @ reluQ) / pad-row, MFMA K=32 ---------------------
// grid (128 bh, 16 chunks of 256 tokens); Q token-major stride 1024.
__global__ __launch_bounds__(256)
void lite_apply(const unsigned short* __restrict__ qb,
                const float* __restrict__ vkws,
                unsigned short* __restrict__ yb) {
    const int bh = blockIdx.x, nb = blockIdx.y;
    const int b = bh >> 5, h = bh & 31;
    __shared__ unsigned short vkh[48 * 32];
    __shared__ unsigned short vkl[48 * 32];
    const int t = threadIdx.x;
    for (int i = t; i < 48 * 32; i += 256) {
        float v = (i < 33 * 32) ? vkws[bh * (33 * 32) + i] : 0.f;
        unsigned short hi = f2bf(v);
        vkh[i] = hi;
        vkl[i] = f2bf(v - bf2f(hi));
    }
    __syncthreads();

    const int lane = t & 63, wv = t >> 6;
    const int col = lane & 15, quad = lane >> 4;
    s8v b0h = *(const s8v*)&vkh[(col)      * 32 + quad * 8];
    s8v b0l = *(const s8v*)&vkl[(col)      * 32 + quad * 8];
    s8v b1h = *(const s8v*)&vkh[(16 + col) * 32 + quad * 8];
    s8v b1l = *(const s8v*)&vkl[(16 + col) * 32 + quad * 8];
    s8v b2h = *(const s8v*)&vkh[(32 + col) * 32 + quad * 8];
    s8v b2l = *(const s8v*)&vkl[(32 + col) * 32 + quad * 8];

    const int ntile = nb * 256 + wv * 64;
#pragma unroll
    for (int mi = 0; mi < 4; ++mi) {
        int tok = ntile + mi * 16 + col;
        const unsigned short* qp =
            qb + (size_t)(b * 4096 + tok) * 1024 + h * 32 + quad * 8;
        s8v a = *(const s8v*)qp;
        f32x4 n0 = {}, n1 = {}, dd = {};
        n0 = __builtin_amdgcn_mfma_f32_16x16x32_bf16(b0h, a, n0, 0, 0, 0);
        n0 = __builtin_amdgcn_mfma_f32_16x16x32_bf16(b0l, a, n0, 0, 0, 0);
        n1 = __builtin_amdgcn_mfma_f32_16x16x32_bf16(b1h, a, n1, 0, 0, 0);
        n1 = __builtin_amdgcn_mfma_f32_16x16x32_bf16(b1l, a, n1, 0, 0, 0);
        dd = __builtin_amdgcn_mfma_f32_16x16x32_bf16(b2h, a, dd, 0, 0, 0);
        dd = __builtin_amdgcn_mfma_f32_16x16x32_bf16(b2l, a, dd, 0, 0, 0);
        float den  = __shfl(dd[0], col, 64);
        float rinv = 1.f / (den + 1e-15f);
        us4 o0, o1;
#pragma unroll
        for (int r = 0; r < 4; ++r) {
            o0[r] = f2bf(n0[r] * rinv);
            o1[r] = f2bf(n1[r] * rinv);
        }
        size_t o = (size_t)(b * 4096 + tok) * 1024 + h * 32;
        *(us4*)&yb[o + quad * 4]      = o0;
        *(us4*)&yb[o + 16 + quad * 4] = o1;
    }
}

// ---------------------------------------------------------------------------
extern "C" void kernel_launch(void* const* d_in, const int* in_sizes, int n_in,
                              void* d_out, int out_size, void* d_ws, size_t ws_size,
                              hipStream_t stream) {
    const float* x     = (const float*)d_in[0];   // (4,4096,1024)
    const float* Wqkv  = (const float*)d_in[1];   // (3072,1024)
    const float* Wproj = (const float*)d_in[2];   // (1024,1024)
    const float* bproj = (const float*)d_in[3];   // (1024,)
    float* out = (float*)d_out;                   // (4,4096,1024) fp32

    const int M = 16384, Cdim = 1024, O1 = 3072;

    unsigned short* xb     = (unsigned short*)d_ws;
    unsigned short* wqkvb  = xb + (size_t)M * Cdim;
    unsigned short* wprojb = wqkvb + (size_t)O1 * Cdim;
    unsigned short* qb     = wprojb + (size_t)Cdim * Cdim;        // Q token-major
    unsigned short* kvT    = qb + (size_t)M * Cdim;               // [4][2048][4096]
    unsigned short* ybuf   = kvT + (size_t)4 * 2048 * 4096;
    float* vkws            = (float*)(ybuf + (size_t)M * Cdim);
    // ws use: ~176 MB

    const int PREP_GROUPS = (16777216 + 3145728 + 1048576 + 135168) / 8;
    prep<<<(PREP_GROUPS + 255) / 256, 256, 0, stream>>>(
        x, Wqkv, Wproj, xb, wqkvb, wprojb, vkws);

    gemm_bt<0><<<(M / 128) * (O1 / 128), 256, 0, stream>>>(
        xb, wqkvb, (void*)qb, kvT, nullptr, M, O1, Cdim);

    lite_vk<<<dim3(128, 8), 256, 0, stream>>>(kvT, vkws);
    lite_apply<<<dim3(128, 16), 256, 0, stream>>>(qb, vkws, ybuf);

    gemm_bt<1><<<(M / 128) * (Cdim / 128), 256, 0, stream>>>(
        ybuf, wprojb, (void*)out, nullptr, bproj, M, Cdim, Cdim);
}